// Round 12
// baseline (232.368 us; speedup 1.0000x reference)
//
#include <hip/hip_runtime.h>
#include <math.h>

typedef unsigned short u16;
typedef unsigned int u32;
typedef short s16x8 __attribute__((ext_vector_type(8)));   // 8 bf16 (4 VGPRs)
typedef float f32x4 __attribute__((ext_vector_type(4)));   // 4 fp32
typedef float f32x16 __attribute__((ext_vector_type(16))); // 16 fp32 (32x32 acc)

static constexpr int Cc = 256;
static constexpr int Ll = 4096;
static constexpr int Bb = 4;

__device__ __forceinline__ u16 f2b(float f) {
    union { float f; unsigned u; } v; v.f = f;
    unsigned r = v.u + 0x7FFF + ((v.u >> 16) & 1);   // RNE
    return (u16)(r >> 16);
}
__device__ __forceinline__ float b2f(u16 h) {
    union { unsigned u; float f; } v; v.u = ((unsigned)h) << 16; return v.f;
}

// async 16B global->LDS (lds dest = wave-uniform base + lane*16)
__device__ __forceinline__ void gload_lds16(const u16* g, u16* l) {
    __builtin_amdgcn_global_load_lds(
        (const __attribute__((address_space(1))) u32*)g,
        (__attribute__((address_space(3))) u32*)l, 16, 0, 0);
}

// pack two f32 -> one u32 of 2x bf16 (RNE); no builtin on gfx950
__device__ __forceinline__ u32 cvtpk(float lo, float hi) {
    u32 r;
    asm volatile("v_cvt_pk_bf16_f32 %0, %1, %2" : "=v"(r) : "v"(lo), "v"(hi));
    return r;
}

// ---------------- Kernel 3': transpose + fused BN partial stats ----------------
__global__ void k_transpose(const float* __restrict__ x, u16* __restrict__ XT,
                            float* __restrict__ sums) {
    int lt = blockIdx.x, ct = blockIdx.y, b = blockIdx.z, t = threadIdx.x;
    int l0 = lt * 64, c0 = ct * 64;
    __shared__ u16 tile[64][65];
    __shared__ float red[2][4][64];
    int ll4 = (t & 15) * 4, cb4 = t >> 4;
    #pragma unroll
    for (int rep = 0; rep < 4; rep++) {
        int cl = rep * 16 + cb4;
        float4 v = *(const float4*)&x[(size_t)(b * Cc + c0 + cl) * Ll + l0 + ll4];
        tile[cl][ll4 + 0] = f2b(v.x);
        tile[cl][ll4 + 1] = f2b(v.y);
        tile[cl][ll4 + 2] = f2b(v.z);
        tile[cl][ll4 + 3] = f2b(v.w);
    }
    __syncthreads();
    int cl2 = t & 63, lb = t >> 6;
    float s = 0.f, s2 = 0.f;
    #pragma unroll
    for (int rep = 0; rep < 16; rep++) {
        int ll2 = lb * 16 + rep;
        u16 hv = tile[cl2][ll2];
        XT[(size_t)(b * Ll + l0 + ll2) * Cc + c0 + cl2] = hv;
        float v = b2f(hv);
        s += v; s2 += v * v;
    }
    red[0][lb][cl2] = s;
    red[1][lb][cl2] = s2;
    __syncthreads();
    if (t < 64) {
        float ss = red[0][0][t] + red[0][1][t] + red[0][2][t] + red[0][3][t];
        float ss2 = red[1][0][t] + red[1][1][t] + red[1][2][t] + red[1][3][t];
        atomicAdd(&sums[c0 + t], ss);
        atomicAdd(&sums[256 + c0 + t], ss2);
    }
}

// ---------------- Kernel 2': fold BN into weights (coefs inline from sums) -----
__global__ void k_fold(const float* __restrict__ wq, const float* __restrict__ bq,
                       const float* __restrict__ wk, const float* __restrict__ bk,
                       const float* __restrict__ wv, const float* __restrict__ bv,
                       const float* __restrict__ wp,
                       const float* __restrict__ gamma, const float* __restrict__ beta,
                       const float* __restrict__ sums,
                       u16* __restrict__ Wqkv, float* __restrict__ biasQKV,
                       u16* __restrict__ Wp16) {
    int m = blockIdx.x, t = threadIdx.x;
    if (m >= 768) {
        int row = m - 768;
        Wp16[row * Cc + t] = f2b(wp[row * Cc + t]);
        return;
    }
    const float inv_n = 1.f / (Bb * Ll);
    float mean = sums[t] * inv_n;
    float var  = sums[256 + t] * inv_n - mean * mean;   // biased, as torch BN
    float rstd = rsqrtf(var + 1e-5f);
    float a  = gamma[t] * rstd;          // coefA
    float cB = beta[t] - mean * a;       // coefB
    int type = m >> 8, row = m & 255;
    const float* W  = (type == 0) ? wq : (type == 1) ? wk : wv;
    const float* bs = (type == 0) ? bq : (type == 1) ? bk : bv;
    float wval = W[row * Cc + t];
    float s2 = (type == 0) ? 0.09016844005556021f : 1.0f;  // (1/sqrt(C)) * log2(e)
    Wqkv[m * Cc + t] = f2b(wval * a * s2);
    __shared__ float rs[256];
    rs[t] = wval * cB;
    __syncthreads();
    for (int off = 128; off > 0; off >>= 1) {
        if (t < off) rs[t] += rs[t + off];
        __syncthreads();
    }
    if (t == 0) biasQKV[m] = (bs[row] + rs[0]) * s2;
}

// ---------------- Kernel 4': QKV GEMM, weight frags double-buffered in regs ----
// Per-o-tile af loads (8x16B from L2, ~200cyc) now issued one tile AHEAD:
// afB(ox+1)/afA(ox+2) fly during the current tile's 32-MFMA burst.
__launch_bounds__(256, 2)
__global__ void k_qkv(const u16* __restrict__ XT, const u16* __restrict__ Wqkv,
                      const float* __restrict__ biasQKV,
                      u16* __restrict__ QT, u16* __restrict__ KT, u16* __restrict__ V) {
    int ly = blockIdx.x, b = blockIdx.y;
    int t = threadIdx.x, w = t >> 6, lane = t & 63;
    int l16 = lane & 15, quad = lane >> 4;
    int l0 = ly * 64;
    __shared__ u16 Xs[64][264];
    {
        int row = t >> 2, chunk = t & 3;
        const u16* src = XT + (size_t)(b * Ll + l0 + row) * Cc + chunk * 64;
        u16* dst = &Xs[row][chunk * 64];
        #pragma unroll
        for (int u = 0; u < 8; u++)
            *(uint4*)(dst + u * 8) = *(const uint4*)(src + u * 8);
    }
    __syncthreads();

#define QKV_LOAD(AF, OX) { \
    const u16* wrow = Wqkv + (size_t)((OX) * 64 + w * 16 + l16) * Cc + quad * 8; \
    _Pragma("unroll") \
    for (int ks = 0; ks < 8; ks++) AF[ks] = *(const s16x8*)(wrow + ks * 32); }

#define QKV_TILE(OX, AF) { \
    int o0 = (OX) * 64; \
    f32x4 acc[4]; \
    _Pragma("unroll") \
    for (int ns = 0; ns < 4; ns++) \
        _Pragma("unroll") \
        for (int r = 0; r < 4; r++) acc[ns][r] = 0.f; \
    _Pragma("unroll") \
    for (int ks = 0; ks < 8; ks++) { \
        _Pragma("unroll") \
        for (int ns = 0; ns < 4; ns++) { \
            s16x8 bf = *(const s16x8*)(&Xs[ns * 16 + l16][ks * 32 + quad * 8]); \
            acc[ns] = __builtin_amdgcn_mfma_f32_16x16x32_bf16(AF[ks], bf, acc[ns], 0, 0, 0); \
        } \
    } \
    int obase = o0 + w * 16 + quad * 4; \
    float bias[4]; \
    _Pragma("unroll") \
    for (int r = 0; r < 4; r++) bias[r] = biasQKV[obase + r]; \
    _Pragma("unroll") \
    for (int ns = 0; ns < 4; ns++) { \
        int l = l0 + ns * 16 + l16; \
        if ((OX) < 8) { \
            u16* dstbase = ((OX) < 4) ? QT : KT; \
            int oo = obase - (((OX) < 4) ? 0 : 256); \
            ushort4 pk; \
            pk.x = f2b(acc[ns][0] + bias[0]); \
            pk.y = f2b(acc[ns][1] + bias[1]); \
            pk.z = f2b(acc[ns][2] + bias[2]); \
            pk.w = f2b(acc[ns][3] + bias[3]); \
            *(ushort4*)(dstbase + (size_t)(b * Ll + l) * Cc + oo) = pk; \
        } else { \
            _Pragma("unroll") \
            for (int r = 0; r < 4; r++) { \
                int o = obase + r - 512; \
                V[(size_t)(b * Cc + o) * Ll + l] = f2b(acc[ns][r] + bias[r]); \
            } \
        } \
    } }

    s16x8 afA[8], afB[8];
    QKV_LOAD(afA, 0);
    for (int ox = 0; ox < 12; ox += 2) {
        QKV_LOAD(afB, ox + 1);          // flies during tile(ox)
        QKV_TILE(ox, afA);
        if (ox + 2 < 12) QKV_LOAD(afA, ox + 2);  // flies during tile(ox+1)
        QKV_TILE(ox + 1, afB);
    }
#undef QKV_LOAD
#undef QKV_TILE
}

// ---------------- Kernel 5: flash attention (R4-verified: 104.7us) -------------
// 256 blocks (b x 32 i-tiles(128) x 2 j-halves), 512 threads (8 waves).
// Swapped QK^T + in-register P; dbuf + split barriers + counted vmcnt.
// Register-topology optimum: 128 arch VGPR + 128 acc = 256/wave = exactly
// 2 waves/SIMD — do not add per-wave state (R7/R10 spills).
__launch_bounds__(512, 2)
__global__ void k_attn(const u16* __restrict__ QT, const u16* __restrict__ KT,
                       const u16* __restrict__ V, u16* __restrict__ Opart,
                       float* __restrict__ Lpart) {
    int id = blockIdx.x;
    int xcd = id & 7, local = id >> 3;      // local 0..31
    int b = xcd >> 1;                       // 2 XCDs per batch: K/V L2-resident
    int u = local * 2 + (xcd & 1);          // 0..63
    int itile = u >> 1;                     // 0..31 (128-row i-tiles)
    int jh = u & 1;
    int t = threadIdx.x, w = t >> 6, lane = t & 63;
    int iw = w & 3, jsub = w >> 2;
    int l31 = lane & 31, hi = lane >> 5;

    __shared__ u16 lds_buf[65536];          // 128KB: Ka[2]|Vb[2]; f32 Omerge in epi
    __shared__ float Lred[2][4][32];

    // Q B-frags: B[col=i=l31][k=ks*16+hi*8+e]
    s16x8 qf[16];
    {
        const u16* qbase = QT + (size_t)(b * Ll + itile * 128 + iw * 32 + l31) * Cc + hi * 8;
        #pragma unroll
        for (int ks = 0; ks < 16; ks++) qf[ks] = *(const s16x8*)(qbase + ks * 16);
    }

    // staging; K frag g=R*8+w -> (gch=g>>4 j-32-tile, gks=g&15 k-step)
    //          V frag g=R*8+w -> (gct=g>>2 c-32-tile, gkj=g&3 j-step)
    const u16* kcur = KT + (size_t)(b * Ll + jh * 2048 + l31) * Cc + hi * 8;
    const u16* vcur = V + (size_t)(b * Cc + l31) * Ll + jh * 2048 + hi * 8;
    int kwo = w * 16;
    size_t vwo = (size_t)((w >> 2) * 32) * Ll + (w & 3) * 16;
    int ldw = w * 512;

#define STAGE_K(c) { u16* kd = lds_buf + (c) * 16384 + ldw;  \
    gload_lds16(kcur + kwo,        kd);          \
    gload_lds16(kcur + kwo + 128,  kd + 4096);   \
    gload_lds16(kcur + kwo + 8192, kd + 8192);   \
    gload_lds16(kcur + kwo + 8320, kd + 12288);  \
    kcur += 64 * Cc; }
#define STAGE_V(c) { u16* vd = lds_buf + 32768 + (c) * 16384 + ldw;  \
    gload_lds16(vcur + vwo,          vd);          \
    gload_lds16(vcur + vwo + 262144, vd + 4096);   \
    gload_lds16(vcur + vwo + 524288, vd + 8192);   \
    gload_lds16(vcur + vwo + 786432, vd + 12288);  \
    vcur += 64; }

    // prologue: K0 V0 K1 V1 (16 staging loads outstanding, 4 per stage per wave)
    STAGE_K(0); STAGE_V(0); STAGE_K(1); STAGE_V(1);

    f32x16 of[8];
    #pragma unroll
    for (int ct = 0; ct < 8; ct++)
        #pragma unroll
        for (int r = 0; r < 16; r++) of[ct][r] = 0.f;
    float lsum = 0.f;

    // wait K0: retire everything older than the youngest 12 (V0,K1,V1) -> K0 + qf
    asm volatile("s_waitcnt vmcnt(12)" ::: "memory");
    __builtin_amdgcn_s_barrier();

    int aoff = jsub * 8192 + lane * 8;      // Ka elem offset (frag = jsub*16+ks)
    int boff = jsub * 1024 + lane * 8;      // Vb elem offset (frag = ct*4+jsub*2+js)

    for (int it = 0; it < 32; it++) {
        const u16* KaC = lds_buf + (it & 1) * 16384;
        const u16* VbC = lds_buf + 32768 + (it & 1) * 16384;

        // ---- phase A: S^T = K * Q^T (two interleaved acc chains) ----
        f32x16 s0, s1;
        #pragma unroll
        for (int r = 0; r < 16; r++) { s0[r] = 0.f; s1[r] = 0.f; }
        __builtin_amdgcn_s_setprio(1);
        #pragma unroll
        for (int ks = 0; ks < 16; ks += 2) {
            s16x8 kf0 = *(const s16x8*)(KaC + aoff + ks * 512);
            s16x8 kf1 = *(const s16x8*)(KaC + aoff + ks * 512 + 512);
            s0 = __builtin_amdgcn_mfma_f32_32x32x16_bf16(kf0, qf[ks], s0, 0, 0, 0);
            s1 = __builtin_amdgcn_mfma_f32_32x32x16_bf16(kf1, qf[ks + 1], s1, 0, 0, 0);
        }
        __builtin_amdgcn_s_setprio(0);

        // ---- softmax (fixed m=0), lane-local; pack P -> PV A-frag words ----
        float p[16];
        #pragma unroll
        for (int r = 0; r < 16; r++) {
            p[r] = __builtin_amdgcn_exp2f(s0[r] + s1[r]);
            lsum += p[r];
        }
        u32 paw[2][4];
        #pragma unroll
        for (int js = 0; js < 2; js++) {
            int o = js * 8;
            u32 a0 = cvtpk(p[o + 0], p[o + 1]);
            u32 b0 = cvtpk(p[o + 4], p[o + 5]);
            u32 a1 = cvtpk(p[o + 2], p[o + 3]);
            u32 b1 = cvtpk(p[o + 6], p[o + 7]);
            asm volatile("v_permlane32_swap_b32 %0, %1" : "+v"(a0), "+v"(b0));
            asm volatile("v_permlane32_swap_b32 %0, %1" : "+v"(a1), "+v"(b1));
            paw[js][0] = a0; paw[js][1] = a1; paw[js][2] = b0; paw[js][3] = b1;
        }

        // B1: my Ka reads retired (lgkm); V(it) resident (vm); then barrier
        asm volatile("s_waitcnt lgkmcnt(0)" ::: "memory");
        if (it < 31) asm volatile("s_waitcnt vmcnt(8)" ::: "memory");
        else         asm volatile("s_waitcnt vmcnt(0)" ::: "memory");
        __builtin_amdgcn_s_barrier();
        if (it < 30) STAGE_K(it & 1);       // K(it+2), flies during phase B

        // ---- phase B: O += P * V^T over this wave's j-half ----
        __builtin_amdgcn_s_setprio(1);
        #pragma unroll
        for (int js = 0; js < 2; js++) {
            union { u32 u[4]; s16x8 v; } pa;
            pa.u[0] = paw[js][0]; pa.u[1] = paw[js][1];
            pa.u[2] = paw[js][2]; pa.u[3] = paw[js][3];
            #pragma unroll
            for (int ct = 0; ct < 8; ct++) {
                s16x8 bf = *(const s16x8*)(VbC + ct * 2048 + boff + js * 512);
                of[ct] = __builtin_amdgcn_mfma_f32_32x32x16_bf16(pa.v, bf, of[ct], 0, 0, 0);
            }
        }
        __builtin_amdgcn_s_setprio(0);

        // B2: my Vb reads retired; K(it+1) resident; then barrier
        if (it < 31) {
            asm volatile("s_waitcnt lgkmcnt(0)" ::: "memory");
            if (it < 30) asm volatile("s_waitcnt vmcnt(8)" ::: "memory");
            else         asm volatile("s_waitcnt vmcnt(4)" ::: "memory");
            __builtin_amdgcn_s_barrier();
            if (it < 30) STAGE_V(it & 1);   // V(it+2), flies during next phase A
        }
    }
#undef STAGE_K
#undef STAGE_V

    // ---- epilogue ----
    // row-sum: lanes l and l+32 hold same row i=l31 (hi halves of the j set)
    lsum += __shfl_xor(lsum, 32);
    if (lane < 32) Lred[jsub][iw][l31] = lsum;
    __syncthreads();                        // drains last Vb reads; Lred visible
    int mi0 = (jh * 4 + b) * Ll + itile * 128;
    if (jsub == 0 && lane < 32)
        Lpart[mi0 + iw * 32 + l31] = Lred[0][iw][l31] + Lred[1][iw][l31];

    // merge partial O across jsub pair via 128KB f32 LDS (reuses Ka/Vb space)
    float* Om = (float*)lds_buf;
    if (jsub == 1) {
        #pragma unroll
        for (int ct = 0; ct < 8; ct++)
            #pragma unroll
            for (int r = 0; r < 16; r++)
                Om[((iw * 8 + ct) * 16 + r) * 64 + lane] = of[ct][r];
    }
    __syncthreads();
    if (jsub == 0) {
        #pragma unroll
        for (int ct = 0; ct < 8; ct++)
            #pragma unroll
            for (int r = 0; r < 16; r++) {
                float val = of[ct][r] + Om[((iw * 8 + ct) * 16 + r) * 64 + lane];
                int rl = (r & 3) + 8 * (r >> 2) + 4 * hi;
                Opart[(size_t)(mi0 + iw * 32 + rl) * 256 + ct * 32 + l31] = f2b(val);
            }
    }
}

// ---------------- Kernel 5b (fallback): merge two j-half partials -> OT ---------
__global__ void k_merge(const u16* __restrict__ Opart, const float* __restrict__ Lpart,
                        u16* __restrict__ OT) {
    int id = blockIdx.x, t = threadIdx.x;
    int b = id >> 6, itile = id & 63;
    int row = t >> 2, seg = t & 3;
    size_t i0 = ((size_t)(0 + b) * 64 + itile) * 64 + row;
    size_t i1 = ((size_t)(4 + b) * 64 + itile) * 64 + row;
    float inv = 1.f / (Lpart[i0] + Lpart[i1]);
    const u16* p0 = Opart + i0 * 256 + seg * 64;
    const u16* p1 = Opart + i1 * 256 + seg * 64;
    u16* dst = OT + (size_t)(b * Ll + itile * 64 + row) * Cc + seg * 64;
    #pragma unroll
    for (int k = 0; k < 8; k++) {
        ushort4 a0 = *(const ushort4*)(p0 + k * 8 + 0);
        ushort4 b0 = *(const ushort4*)(p0 + k * 8 + 4);
        ushort4 a1 = *(const ushort4*)(p1 + k * 8 + 0);
        ushort4 b1 = *(const ushort4*)(p1 + k * 8 + 4);
        ushort4 oA, oB;
        oA.x = f2b((b2f(a0.x) + b2f(a1.x)) * inv);
        oA.y = f2b((b2f(a0.y) + b2f(a1.y)) * inv);
        oA.z = f2b((b2f(a0.z) + b2f(a1.z)) * inv);
        oA.w = f2b((b2f(a0.w) + b2f(a1.w)) * inv);
        oB.x = f2b((b2f(b0.x) + b2f(b1.x)) * inv);
        oB.y = f2b((b2f(b0.y) + b2f(b1.y)) * inv);
        oB.z = f2b((b2f(b0.z) + b2f(b1.z)) * inv);
        oB.w = f2b((b2f(b0.w) + b2f(b1.w)) * inv);
        *(ushort4*)(dst + k * 8 + 0) = oA;
        *(ushort4*)(dst + k * 8 + 4) = oB;
    }
}

// ---------------- Kernel 6': projection, weight frags double-buffered in regs --
__launch_bounds__(256, 2)
__global__ void k_proj(const u16* __restrict__ OT, const u16* __restrict__ Opart,
                       const float* __restrict__ Lpart, int fused,
                       const u16* __restrict__ Wp16,
                       const float* __restrict__ bp, const float* __restrict__ x,
                       float* __restrict__ out) {
    int ly = blockIdx.x, b = blockIdx.y;
    int t = threadIdx.x, w = t >> 6, lane = t & 63;
    int l16 = lane & 15, quad = lane >> 4;
    int l0 = ly * 64;
    __shared__ u16 Os[64][264];
    {
        int row = t >> 2, chunk = t & 3;
        u16* dst = &Os[row][chunk * 64];
        if (fused) {
            size_t i0 = ((size_t)(0 + b) * Ll + l0 + row);
            size_t i1 = ((size_t)(4 + b) * Ll + l0 + row);
            float inv = 1.f / (Lpart[i0] + Lpart[i1]);
            const u16* p0 = Opart + i0 * 256 + chunk * 64;
            const u16* p1 = Opart + i1 * 256 + chunk * 64;
            #pragma unroll
            for (int k = 0; k < 8; k++) {
                ushort4 a0 = *(const ushort4*)(p0 + k * 8 + 0);
                ushort4 b0 = *(const ushort4*)(p0 + k * 8 + 4);
                ushort4 a1 = *(const ushort4*)(p1 + k * 8 + 0);
                ushort4 b1 = *(const ushort4*)(p1 + k * 8 + 4);
                ushort4 oA, oB;
                oA.x = f2b((b2f(a0.x) + b2f(a1.x)) * inv);
                oA.y = f2b((b2f(a0.y) + b2f(a1.y)) * inv);
                oA.z = f2b((b2f(a0.z) + b2f(a1.z)) * inv);
                oA.w = f2b((b2f(a0.w) + b2f(a1.w)) * inv);
                oB.x = f2b((b2f(b0.x) + b2f(b1.x)) * inv);
                oB.y = f2b((b2f(b0.y) + b2f(b1.y)) * inv);
                oB.z = f2b((b2f(b0.z) + b2f(b1.z)) * inv);
                oB.w = f2b((b2f(b0.w) + b2f(b1.w)) * inv);
                *(ushort4*)(dst + k * 8 + 0) = oA;
                *(ushort4*)(dst + k * 8 + 4) = oB;
            }
        } else {
            const u16* src = OT + (size_t)(b * Ll + l0 + row) * Cc + chunk * 64;
            #pragma unroll
            for (int u = 0; u < 8; u++)
                *(uint4*)(dst + u * 8) = *(const uint4*)(src + u * 8);
        }
    }
    __syncthreads();

#define PROJ_LOAD(AF, OX) { \
    const u16* wrow = Wp16 + (size_t)((OX) * 64 + w * 16 + l16) * Cc + quad * 8; \
    _Pragma("unroll") \
    for (int ks = 0; ks < 8; ks++) AF[ks] = *(const s16x8*)(wrow + ks * 32); }

#define PROJ_TILE(OX, AF) { \
    f32x4 acc[4]; \
    _Pragma("unroll") \
    for (int ns = 0; ns < 4; ns++) \
        _Pragma("unroll") \
        for (int r = 0; r < 4; r++) acc[ns][r] = 0.f; \
    _Pragma("unroll") \
    for (int ks = 0; ks < 8; ks++) { \
        _Pragma("unroll") \
        for (int ns = 0; ns < 4; ns++) { \
            s16x8 bf = *(const s16x8*)(&Os[ns * 16 + l16][ks * 32 + quad * 8]); \
            acc[ns] = __builtin_amdgcn_mfma_f32_16x16x32_bf16(AF[ks], bf, acc[ns], 0, 0, 0); \
        } \
    } \
    int ob = (OX) * 64 + w * 16 + quad * 4; \
    float bias[4]; \
    _Pragma("unroll") \
    for (int r = 0; r < 4; r++) bias[r] = bp[ob + r]; \
    _Pragma("unroll") \
    for (int ns = 0; ns < 4; ns++) { \
        _Pragma("unroll") \
        for (int r = 0; r < 4; r++) { \
            int o = ob + r; \
            int l = l0 + ns * 16 + l16; \
            size_t idx = (size_t)(b * Cc + o) * Ll + l; \
            out[idx] = x[idx] + bias[r] + acc[ns][r]; \
        } \
    } }

    s16x8 afA[8], afB[8];
    PROJ_LOAD(afA, 0);
    for (int ox = 0; ox < 4; ox += 2) {
        PROJ_LOAD(afB, ox + 1);
        PROJ_TILE(ox, afA);
        if (ox + 2 < 4) PROJ_LOAD(afA, ox + 2);
        PROJ_TILE(ox + 1, afB);
    }
#undef PROJ_LOAD
#undef PROJ_TILE
}

// ---------------- launch ----------------
extern "C" void kernel_launch(void* const* d_in, const int* in_sizes, int n_in,
                              void* d_out, int out_size, void* d_ws, size_t ws_size,
                              hipStream_t stream) {
    const float* x     = (const float*)d_in[0];
    const float* gamma = (const float*)d_in[1];
    const float* beta  = (const float*)d_in[2];
    const float* wq    = (const float*)d_in[3];
    const float* bq    = (const float*)d_in[4];
    const float* wk    = (const float*)d_in[5];
    const float* bk    = (const float*)d_in[6];
    const float* wv    = (const float*)d_in[7];
    const float* bv    = (const float*)d_in[8];
    const float* wp    = (const float*)d_in[9];
    const float* bp    = (const float*)d_in[10];
    float* out = (float*)d_out;
    char* ws = (char*)d_ws;

    float* sums    = (float*)(ws + 0);         // 512 f32 (sum, sumsq)
    float* biasQKV = (float*)(ws + 2048);
    u16*   Wqkv    = (u16*)(ws + 8192);
    u16*   Wp16    = (u16*)(ws + 401408);
    u16*   XT      = (u16*)(ws + 532480);      // [B][L][C] bf16 (8.39MB)
    u16*   QT      = (u16*)(ws + 8921088);
    u16*   KT      = (u16*)(ws + 17309696);
    u16*   V       = (u16*)(ws + 25698304);    // ends at 34086912
    u16*   OT      = XT;                       // alias: XT dead after k_qkv

    // fused path: Opart (16.78MB) + Lpart (128KB) live in ws past V
    const size_t opart_off = 34086912;
    const size_t lpart_off = opart_off + 16777216;
    const size_t needed    = lpart_off + 131072;
    int fused = (ws_size >= needed) ? 1 : 0;
    u16*   Opart = fused ? (u16*)(ws + opart_off) : (u16*)d_out;
    float* Lpart = (float*)(ws + (fused ? lpart_off : opart_off));

    (void)hipMemsetAsync(sums, 0, 2048, stream);
    k_transpose<<<dim3(64, 4, 4), 256, 0, stream>>>(x, XT, sums);
    k_fold<<<1024, 256, 0, stream>>>(wq, bq, wk, bk, wv, bv, wp, gamma, beta,
                                     sums, Wqkv, biasQKV, Wp16);
    k_qkv<<<dim3(64, 4), 256, 0, stream>>>(XT, Wqkv, biasQKV, QT, KT, V);
    k_attn<<<256, 512, 0, stream>>>(QT, KT, V, Opart, Lpart);
    if (!fused)
        k_merge<<<256, 256, 0, stream>>>(Opart, Lpart, OT);
    k_proj<<<dim3(64, 4), 256, 0, stream>>>(OT, Opart, Lpart, fused,
                                            Wp16, bp, x, out);
}

// Round 13
// 224.121 us; speedup vs baseline: 1.0368x; 1.0368x over previous
//
#include <hip/hip_runtime.h>
#include <math.h>

typedef unsigned short u16;
typedef unsigned int u32;
typedef short s16x8 __attribute__((ext_vector_type(8)));   // 8 bf16 (4 VGPRs)
typedef float f32x4 __attribute__((ext_vector_type(4)));   // 4 fp32
typedef float f32x16 __attribute__((ext_vector_type(16))); // 16 fp32 (32x32 acc)

static constexpr int Cc = 256;
static constexpr int Ll = 4096;
static constexpr int Bb = 4;

__device__ __forceinline__ u16 f2b(float f) {
    union { float f; unsigned u; } v; v.f = f;
    unsigned r = v.u + 0x7FFF + ((v.u >> 16) & 1);   // RNE
    return (u16)(r >> 16);
}
__device__ __forceinline__ float b2f(u16 h) {
    union { unsigned u; float f; } v; v.u = ((unsigned)h) << 16; return v.f;
}

// async 16B global->LDS (lds dest = wave-uniform base + lane*16)
__device__ __forceinline__ void gload_lds16(const u16* g, u16* l) {
    __builtin_amdgcn_global_load_lds(
        (const __attribute__((address_space(1))) u32*)g,
        (__attribute__((address_space(3))) u32*)l, 16, 0, 0);
}

// pack two f32 -> one u32 of 2x bf16 (RNE); no builtin on gfx950
__device__ __forceinline__ u32 cvtpk(float lo, float hi) {
    u32 r;
    asm volatile("v_cvt_pk_bf16_f32 %0, %1, %2" : "=v"(r) : "v"(lo), "v"(hi));
    return r;
}

// ---------------- Kernel 3': transpose + fused BN partial stats ----------------
__global__ void k_transpose(const float* __restrict__ x, u16* __restrict__ XT,
                            float* __restrict__ sums) {
    int lt = blockIdx.x, ct = blockIdx.y, b = blockIdx.z, t = threadIdx.x;
    int l0 = lt * 64, c0 = ct * 64;
    __shared__ u16 tile[64][65];
    __shared__ float red[2][4][64];
    int ll4 = (t & 15) * 4, cb4 = t >> 4;
    #pragma unroll
    for (int rep = 0; rep < 4; rep++) {
        int cl = rep * 16 + cb4;
        float4 v = *(const float4*)&x[(size_t)(b * Cc + c0 + cl) * Ll + l0 + ll4];
        tile[cl][ll4 + 0] = f2b(v.x);
        tile[cl][ll4 + 1] = f2b(v.y);
        tile[cl][ll4 + 2] = f2b(v.z);
        tile[cl][ll4 + 3] = f2b(v.w);
    }
    __syncthreads();
    int cl2 = t & 63, lb = t >> 6;
    float s = 0.f, s2 = 0.f;
    #pragma unroll
    for (int rep = 0; rep < 16; rep++) {
        int ll2 = lb * 16 + rep;
        u16 hv = tile[cl2][ll2];
        XT[(size_t)(b * Ll + l0 + ll2) * Cc + c0 + cl2] = hv;
        float v = b2f(hv);
        s += v; s2 += v * v;
    }
    red[0][lb][cl2] = s;
    red[1][lb][cl2] = s2;
    __syncthreads();
    if (t < 64) {
        float ss = red[0][0][t] + red[0][1][t] + red[0][2][t] + red[0][3][t];
        float ss2 = red[1][0][t] + red[1][1][t] + red[1][2][t] + red[1][3][t];
        atomicAdd(&sums[c0 + t], ss);
        atomicAdd(&sums[256 + c0 + t], ss2);
    }
}

// ---------------- Kernel 2': fold BN into weights (coefs inline from sums) -----
// Block reduction: wave shfl_xor (6 steps) + 1 barrier (was 8-barrier LDS tree).
__global__ void k_fold(const float* __restrict__ wq, const float* __restrict__ bq,
                       const float* __restrict__ wk, const float* __restrict__ bk,
                       const float* __restrict__ wv, const float* __restrict__ bv,
                       const float* __restrict__ wp,
                       const float* __restrict__ gamma, const float* __restrict__ beta,
                       const float* __restrict__ sums,
                       u16* __restrict__ Wqkv, float* __restrict__ biasQKV,
                       u16* __restrict__ Wp16) {
    int m = blockIdx.x, t = threadIdx.x;
    if (m >= 768) {
        int row = m - 768;
        Wp16[row * Cc + t] = f2b(wp[row * Cc + t]);
        return;
    }
    const float inv_n = 1.f / (Bb * Ll);
    float mean = sums[t] * inv_n;
    float var  = sums[256 + t] * inv_n - mean * mean;   // biased, as torch BN
    float rstd = rsqrtf(var + 1e-5f);
    float a  = gamma[t] * rstd;          // coefA
    float cB = beta[t] - mean * a;       // coefB
    int type = m >> 8, row = m & 255;
    const float* W  = (type == 0) ? wq : (type == 1) ? wk : wv;
    const float* bs = (type == 0) ? bq : (type == 1) ? bk : bv;
    float wval = W[row * Cc + t];
    float s2 = (type == 0) ? 0.09016844005556021f : 1.0f;  // (1/sqrt(C)) * log2(e)
    Wqkv[m * Cc + t] = f2b(wval * a * s2);
    float v = wval * cB;
    #pragma unroll
    for (int off = 32; off > 0; off >>= 1) v += __shfl_xor(v, off);
    __shared__ float ws4[4];
    if ((t & 63) == 0) ws4[t >> 6] = v;
    __syncthreads();
    if (t == 0) biasQKV[m] = (bs[row] + ws4[0] + ws4[1] + ws4[2] + ws4[3]) * s2;
}

// ---------------- Kernel 4': QKV GEMM, XT staged once, loop over o-tiles ------
__launch_bounds__(256, 2)
__global__ void k_qkv(const u16* __restrict__ XT, const u16* __restrict__ Wqkv,
                      const float* __restrict__ biasQKV,
                      u16* __restrict__ QT, u16* __restrict__ KT, u16* __restrict__ V) {
    int ly = blockIdx.x, b = blockIdx.y;
    int t = threadIdx.x, w = t >> 6, lane = t & 63;
    int l16 = lane & 15, quad = lane >> 4;
    int l0 = ly * 64;
    __shared__ u16 Xs[64][264];
    {
        int row = t >> 2, chunk = t & 3;
        const u16* src = XT + (size_t)(b * Ll + l0 + row) * Cc + chunk * 64;
        u16* dst = &Xs[row][chunk * 64];
        #pragma unroll
        for (int u = 0; u < 8; u++)
            *(uint4*)(dst + u * 8) = *(const uint4*)(src + u * 8);
    }
    __syncthreads();
    for (int ox = 0; ox < 12; ox++) {
        int o0 = ox * 64;
        s16x8 af[8];
        {
            const u16* wrow = Wqkv + (size_t)(o0 + w * 16 + l16) * Cc + quad * 8;
            #pragma unroll
            for (int ks = 0; ks < 8; ks++) af[ks] = *(const s16x8*)(wrow + ks * 32);
        }
        f32x4 acc[4];
        #pragma unroll
        for (int ns = 0; ns < 4; ns++)
            #pragma unroll
            for (int r = 0; r < 4; r++) acc[ns][r] = 0.f;
        #pragma unroll
        for (int ks = 0; ks < 8; ks++) {
            #pragma unroll
            for (int ns = 0; ns < 4; ns++) {
                s16x8 bf = *(const s16x8*)(&Xs[ns * 16 + l16][ks * 32 + quad * 8]);
                acc[ns] = __builtin_amdgcn_mfma_f32_16x16x32_bf16(af[ks], bf, acc[ns], 0, 0, 0);
            }
        }
        int obase = o0 + w * 16 + quad * 4;
        float bias[4];
        #pragma unroll
        for (int r = 0; r < 4; r++) bias[r] = biasQKV[obase + r];
        #pragma unroll
        for (int ns = 0; ns < 4; ns++) {
            int l = l0 + ns * 16 + l16;
            if (ox < 8) {
                u16* dstbase = (ox < 4) ? QT : KT;
                int oo = obase - ((ox < 4) ? 0 : 256);
                ushort4 pk;
                pk.x = f2b(acc[ns][0] + bias[0]);
                pk.y = f2b(acc[ns][1] + bias[1]);
                pk.z = f2b(acc[ns][2] + bias[2]);
                pk.w = f2b(acc[ns][3] + bias[3]);
                *(ushort4*)(dstbase + (size_t)(b * Ll + l) * Cc + oo) = pk;
            } else {
                #pragma unroll
                for (int r = 0; r < 4; r++) {
                    int o = obase + r - 512;
                    V[(size_t)(b * Cc + o) * Ll + l] = f2b(acc[ns][r] + bias[r]);
                }
            }
        }
    }
}

// ---------------- Kernel 5: flash attention (R4-verified: 104.7us) -------------
// 256 blocks (b x 32 i-tiles(128) x 2 j-halves), 512 threads (8 waves).
// Swapped QK^T + in-register P; dbuf + split barriers + counted vmcnt.
// Register-topology optimum: 128 arch VGPR + 128 acc = 256/wave = exactly
// 2 waves/SIMD — do not add per-wave state (R7/R10 spills).
__launch_bounds__(512, 2)
__global__ void k_attn(const u16* __restrict__ QT, const u16* __restrict__ KT,
                       const u16* __restrict__ V, u16* __restrict__ Opart,
                       float* __restrict__ Lpart) {
    int id = blockIdx.x;
    int xcd = id & 7, local = id >> 3;      // local 0..31
    int b = xcd >> 1;                       // 2 XCDs per batch: K/V L2-resident
    int u = local * 2 + (xcd & 1);          // 0..63
    int itile = u >> 1;                     // 0..31 (128-row i-tiles)
    int jh = u & 1;
    int t = threadIdx.x, w = t >> 6, lane = t & 63;
    int iw = w & 3, jsub = w >> 2;
    int l31 = lane & 31, hi = lane >> 5;

    __shared__ u16 lds_buf[65536];          // 128KB: Ka[2]|Vb[2]; f32 Omerge in epi
    __shared__ float Lred[2][4][32];

    // Q B-frags: B[col=i=l31][k=ks*16+hi*8+e]
    s16x8 qf[16];
    {
        const u16* qbase = QT + (size_t)(b * Ll + itile * 128 + iw * 32 + l31) * Cc + hi * 8;
        #pragma unroll
        for (int ks = 0; ks < 16; ks++) qf[ks] = *(const s16x8*)(qbase + ks * 16);
    }

    // staging; K frag g=R*8+w -> (gch=g>>4 j-32-tile, gks=g&15 k-step)
    //          V frag g=R*8+w -> (gct=g>>2 c-32-tile, gkj=g&3 j-step)
    const u16* kcur = KT + (size_t)(b * Ll + jh * 2048 + l31) * Cc + hi * 8;
    const u16* vcur = V + (size_t)(b * Cc + l31) * Ll + jh * 2048 + hi * 8;
    int kwo = w * 16;
    size_t vwo = (size_t)((w >> 2) * 32) * Ll + (w & 3) * 16;
    int ldw = w * 512;

#define STAGE_K(c) { u16* kd = lds_buf + (c) * 16384 + ldw;  \
    gload_lds16(kcur + kwo,        kd);          \
    gload_lds16(kcur + kwo + 128,  kd + 4096);   \
    gload_lds16(kcur + kwo + 8192, kd + 8192);   \
    gload_lds16(kcur + kwo + 8320, kd + 12288);  \
    kcur += 64 * Cc; }
#define STAGE_V(c) { u16* vd = lds_buf + 32768 + (c) * 16384 + ldw;  \
    gload_lds16(vcur + vwo,          vd);          \
    gload_lds16(vcur + vwo + 262144, vd + 4096);   \
    gload_lds16(vcur + vwo + 524288, vd + 8192);   \
    gload_lds16(vcur + vwo + 786432, vd + 12288);  \
    vcur += 64; }

    // prologue: K0 V0 K1 V1 (16 staging loads outstanding, 4 per stage per wave)
    STAGE_K(0); STAGE_V(0); STAGE_K(1); STAGE_V(1);

    f32x16 of[8];
    #pragma unroll
    for (int ct = 0; ct < 8; ct++)
        #pragma unroll
        for (int r = 0; r < 16; r++) of[ct][r] = 0.f;
    float lsum = 0.f;

    // wait K0: retire everything older than the youngest 12 (V0,K1,V1) -> K0 + qf
    asm volatile("s_waitcnt vmcnt(12)" ::: "memory");
    __builtin_amdgcn_s_barrier();

    int aoff = jsub * 8192 + lane * 8;      // Ka elem offset (frag = jsub*16+ks)
    int boff = jsub * 1024 + lane * 8;      // Vb elem offset (frag = ct*4+jsub*2+js)

    for (int it = 0; it < 32; it++) {
        const u16* KaC = lds_buf + (it & 1) * 16384;
        const u16* VbC = lds_buf + 32768 + (it & 1) * 16384;

        // ---- phase A: S^T = K * Q^T (two interleaved acc chains) ----
        f32x16 s0, s1;
        #pragma unroll
        for (int r = 0; r < 16; r++) { s0[r] = 0.f; s1[r] = 0.f; }
        __builtin_amdgcn_s_setprio(1);
        #pragma unroll
        for (int ks = 0; ks < 16; ks += 2) {
            s16x8 kf0 = *(const s16x8*)(KaC + aoff + ks * 512);
            s16x8 kf1 = *(const s16x8*)(KaC + aoff + ks * 512 + 512);
            s0 = __builtin_amdgcn_mfma_f32_32x32x16_bf16(kf0, qf[ks], s0, 0, 0, 0);
            s1 = __builtin_amdgcn_mfma_f32_32x32x16_bf16(kf1, qf[ks + 1], s1, 0, 0, 0);
        }
        __builtin_amdgcn_s_setprio(0);

        // ---- softmax (fixed m=0), lane-local; pack P -> PV A-frag words ----
        float p[16];
        #pragma unroll
        for (int r = 0; r < 16; r++) {
            p[r] = __builtin_amdgcn_exp2f(s0[r] + s1[r]);
            lsum += p[r];
        }
        u32 paw[2][4];
        #pragma unroll
        for (int js = 0; js < 2; js++) {
            int o = js * 8;
            u32 a0 = cvtpk(p[o + 0], p[o + 1]);
            u32 b0 = cvtpk(p[o + 4], p[o + 5]);
            u32 a1 = cvtpk(p[o + 2], p[o + 3]);
            u32 b1 = cvtpk(p[o + 6], p[o + 7]);
            asm volatile("v_permlane32_swap_b32 %0, %1" : "+v"(a0), "+v"(b0));
            asm volatile("v_permlane32_swap_b32 %0, %1" : "+v"(a1), "+v"(b1));
            paw[js][0] = a0; paw[js][1] = a1; paw[js][2] = b0; paw[js][3] = b1;
        }

        // B1: my Ka reads retired (lgkm); V(it) resident (vm); then barrier
        asm volatile("s_waitcnt lgkmcnt(0)" ::: "memory");
        if (it < 31) asm volatile("s_waitcnt vmcnt(8)" ::: "memory");
        else         asm volatile("s_waitcnt vmcnt(0)" ::: "memory");
        __builtin_amdgcn_s_barrier();
        if (it < 30) STAGE_K(it & 1);       // K(it+2), flies during phase B

        // ---- phase B: O += P * V^T over this wave's j-half ----
        __builtin_amdgcn_s_setprio(1);
        #pragma unroll
        for (int js = 0; js < 2; js++) {
            union { u32 u[4]; s16x8 v; } pa;
            pa.u[0] = paw[js][0]; pa.u[1] = paw[js][1];
            pa.u[2] = paw[js][2]; pa.u[3] = paw[js][3];
            #pragma unroll
            for (int ct = 0; ct < 8; ct++) {
                s16x8 bf = *(const s16x8*)(VbC + ct * 2048 + boff + js * 512);
                of[ct] = __builtin_amdgcn_mfma_f32_32x32x16_bf16(pa.v, bf, of[ct], 0, 0, 0);
            }
        }
        __builtin_amdgcn_s_setprio(0);

        // B2: my Vb reads retired; K(it+1) resident; then barrier
        if (it < 31) {
            asm volatile("s_waitcnt lgkmcnt(0)" ::: "memory");
            if (it < 30) asm volatile("s_waitcnt vmcnt(8)" ::: "memory");
            else         asm volatile("s_waitcnt vmcnt(4)" ::: "memory");
            __builtin_amdgcn_s_barrier();
            if (it < 30) STAGE_V(it & 1);   // V(it+2), flies during next phase A
        }
    }
#undef STAGE_K
#undef STAGE_V

    // ---- epilogue ----
    // row-sum: lanes l and l+32 hold same row i=l31 (hi halves of the j set)
    lsum += __shfl_xor(lsum, 32);
    if (lane < 32) Lred[jsub][iw][l31] = lsum;
    __syncthreads();                        // drains last Vb reads; Lred visible
    int mi0 = (jh * 4 + b) * Ll + itile * 128;
    if (jsub == 0 && lane < 32)
        Lpart[mi0 + iw * 32 + l31] = Lred[0][iw][l31] + Lred[1][iw][l31];

    // merge partial O across jsub pair via 128KB f32 LDS (reuses Ka/Vb space)
    float* Om = (float*)lds_buf;
    if (jsub == 1) {
        #pragma unroll
        for (int ct = 0; ct < 8; ct++)
            #pragma unroll
            for (int r = 0; r < 16; r++)
                Om[((iw * 8 + ct) * 16 + r) * 64 + lane] = of[ct][r];
    }
    __syncthreads();
    if (jsub == 0) {
        #pragma unroll
        for (int ct = 0; ct < 8; ct++)
            #pragma unroll
            for (int r = 0; r < 16; r++) {
                float val = of[ct][r] + Om[((iw * 8 + ct) * 16 + r) * 64 + lane];
                int rl = (r & 3) + 8 * (r >> 2) + 4 * hi;
                Opart[(size_t)(mi0 + iw * 32 + rl) * 256 + ct * 32 + l31] = f2b(val);
            }
    }
}

// ---------------- Kernel 5b (fallback): merge two j-half partials -> OT ---------
__global__ void k_merge(const u16* __restrict__ Opart, const float* __restrict__ Lpart,
                        u16* __restrict__ OT) {
    int id = blockIdx.x, t = threadIdx.x;
    int b = id >> 6, itile = id & 63;
    int row = t >> 2, seg = t & 3;
    size_t i0 = ((size_t)(0 + b) * 64 + itile) * 64 + row;
    size_t i1 = ((size_t)(4 + b) * 64 + itile) * 64 + row;
    float inv = 1.f / (Lpart[i0] + Lpart[i1]);
    const u16* p0 = Opart + i0 * 256 + seg * 64;
    const u16* p1 = Opart + i1 * 256 + seg * 64;
    u16* dst = OT + (size_t)(b * Ll + itile * 64 + row) * Cc + seg * 64;
    #pragma unroll
    for (int k = 0; k < 8; k++) {
        ushort4 a0 = *(const ushort4*)(p0 + k * 8 + 0);
        ushort4 b0 = *(const ushort4*)(p0 + k * 8 + 4);
        ushort4 a1 = *(const ushort4*)(p1 + k * 8 + 0);
        ushort4 b1 = *(const ushort4*)(p1 + k * 8 + 4);
        ushort4 oA, oB;
        oA.x = f2b((b2f(a0.x) + b2f(a1.x)) * inv);
        oA.y = f2b((b2f(a0.y) + b2f(a1.y)) * inv);
        oA.z = f2b((b2f(a0.z) + b2f(a1.z)) * inv);
        oA.w = f2b((b2f(a0.w) + b2f(a1.w)) * inv);
        oB.x = f2b((b2f(b0.x) + b2f(b1.x)) * inv);
        oB.y = f2b((b2f(b0.y) + b2f(b1.y)) * inv);
        oB.z = f2b((b2f(b0.z) + b2f(b1.z)) * inv);
        oB.w = f2b((b2f(b0.w) + b2f(b1.w)) * inv);
        *(ushort4*)(dst + k * 8 + 0) = oA;
        *(ushort4*)(dst + k * 8 + 4) = oB;
    }
}

// ---------------- Kernel 6': projection, OT staged once, loop over o-tiles ------
__launch_bounds__(256, 2)
__global__ void k_proj(const u16* __restrict__ OT, const u16* __restrict__ Opart,
                       const float* __restrict__ Lpart, int fused,
                       const u16* __restrict__ Wp16,
                       const float* __restrict__ bp, const float* __restrict__ x,
                       float* __restrict__ out) {
    int ly = blockIdx.x, b = blockIdx.y;
    int t = threadIdx.x, w = t >> 6, lane = t & 63;
    int l16 = lane & 15, quad = lane >> 4;
    int l0 = ly * 64;
    __shared__ u16 Os[64][264];
    {
        int row = t >> 2, chunk = t & 3;
        u16* dst = &Os[row][chunk * 64];
        if (fused) {
            size_t i0 = ((size_t)(0 + b) * Ll + l0 + row);
            size_t i1 = ((size_t)(4 + b) * Ll + l0 + row);
            float inv = 1.f / (Lpart[i0] + Lpart[i1]);
            const u16* p0 = Opart + i0 * 256 + chunk * 64;
            const u16* p1 = Opart + i1 * 256 + chunk * 64;
            #pragma unroll
            for (int k = 0; k < 8; k++) {
                ushort4 a0 = *(const ushort4*)(p0 + k * 8 + 0);
                ushort4 b0 = *(const ushort4*)(p0 + k * 8 + 4);
                ushort4 a1 = *(const ushort4*)(p1 + k * 8 + 0);
                ushort4 b1 = *(const ushort4*)(p1 + k * 8 + 4);
                ushort4 oA, oB;
                oA.x = f2b((b2f(a0.x) + b2f(a1.x)) * inv);
                oA.y = f2b((b2f(a0.y) + b2f(a1.y)) * inv);
                oA.z = f2b((b2f(a0.z) + b2f(a1.z)) * inv);
                oA.w = f2b((b2f(a0.w) + b2f(a1.w)) * inv);
                oB.x = f2b((b2f(b0.x) + b2f(b1.x)) * inv);
                oB.y = f2b((b2f(b0.y) + b2f(b1.y)) * inv);
                oB.z = f2b((b2f(b0.z) + b2f(b1.z)) * inv);
                oB.w = f2b((b2f(b0.w) + b2f(b1.w)) * inv);
                *(ushort4*)(dst + k * 8 + 0) = oA;
                *(ushort4*)(dst + k * 8 + 4) = oB;
            }
        } else {
            const u16* src = OT + (size_t)(b * Ll + l0 + row) * Cc + chunk * 64;
            #pragma unroll
            for (int u = 0; u < 8; u++)
                *(uint4*)(dst + u * 8) = *(const uint4*)(src + u * 8);
        }
    }
    __syncthreads();
    for (int ox = 0; ox < 4; ox++) {
        int o0 = ox * 64;
        s16x8 af[8];
        {
            const u16* wrow = Wp16 + (size_t)(o0 + w * 16 + l16) * Cc + quad * 8;
            #pragma unroll
            for (int ks = 0; ks < 8; ks++) af[ks] = *(const s16x8*)(wrow + ks * 32);
        }
        f32x4 acc[4];
        #pragma unroll
        for (int ns = 0; ns < 4; ns++)
            #pragma unroll
            for (int r = 0; r < 4; r++) acc[ns][r] = 0.f;
        #pragma unroll
        for (int ks = 0; ks < 8; ks++) {
            #pragma unroll
            for (int ns = 0; ns < 4; ns++) {
                s16x8 bf = *(const s16x8*)(&Os[ns * 16 + l16][ks * 32 + quad * 8]);
                acc[ns] = __builtin_amdgcn_mfma_f32_16x16x32_bf16(af[ks], bf, acc[ns], 0, 0, 0);
            }
        }
        int ob = o0 + w * 16 + quad * 4;
        float bias[4];
        #pragma unroll
        for (int r = 0; r < 4; r++) bias[r] = bp[ob + r];
        #pragma unroll
        for (int ns = 0; ns < 4; ns++) {
            #pragma unroll
            for (int r = 0; r < 4; r++) {
                int o = ob + r;
                int l = l0 + ns * 16 + l16;
                size_t idx = (size_t)(b * Cc + o) * Ll + l;
                out[idx] = x[idx] + bias[r] + acc[ns][r];
            }
        }
    }
}

// ---------------- launch ----------------
extern "C" void kernel_launch(void* const* d_in, const int* in_sizes, int n_in,
                              void* d_out, int out_size, void* d_ws, size_t ws_size,
                              hipStream_t stream) {
    const float* x     = (const float*)d_in[0];
    const float* gamma = (const float*)d_in[1];
    const float* beta  = (const float*)d_in[2];
    const float* wq    = (const float*)d_in[3];
    const float* bq    = (const float*)d_in[4];
    const float* wk    = (const float*)d_in[5];
    const float* bk    = (const float*)d_in[6];
    const float* wv    = (const float*)d_in[7];
    const float* bv    = (const float*)d_in[8];
    const float* wp    = (const float*)d_in[9];
    const float* bp    = (const float*)d_in[10];
    float* out = (float*)d_out;
    char* ws = (char*)d_ws;

    float* sums    = (float*)(ws + 0);         // 512 f32 (sum, sumsq)
    float* biasQKV = (float*)(ws + 2048);
    u16*   Wqkv    = (u16*)(ws + 8192);
    u16*   Wp16    = (u16*)(ws + 401408);
    u16*   XT      = (u16*)(ws + 532480);      // [B][L][C] bf16 (8.39MB)
    u16*   QT      = (u16*)(ws + 8921088);
    u16*   KT      = (u16*)(ws + 17309696);
    u16*   V       = (u16*)(ws + 25698304);    // ends at 34086912
    u16*   OT      = XT;                       // alias: XT dead after k_qkv

    // fused path: Opart (16.78MB) + Lpart (128KB) live in ws past V
    const size_t opart_off = 34086912;
    const size_t lpart_off = opart_off + 16777216;
    const size_t needed    = lpart_off + 131072;
    int fused = (ws_size >= needed) ? 1 : 0;
    u16*   Opart = fused ? (u16*)(ws + opart_off) : (u16*)d_out;
    float* Lpart = (float*)(ws + (fused ? lpart_off : opart_off));

    (void)hipMemsetAsync(sums, 0, 2048, stream);
    k_transpose<<<dim3(64, 4, 4), 256, 0, stream>>>(x, XT, sums);
    k_fold<<<1024, 256, 0, stream>>>(wq, bq, wk, bk, wv, bv, wp, gamma, beta,
                                     sums, Wqkv, biasQKV, Wp16);
    k_qkv<<<dim3(64, 4), 256, 0, stream>>>(XT, Wqkv, biasQKV, QT, KT, V);
    k_attn<<<256, 512, 0, stream>>>(QT, KT, V, Opart, Lpart);
    if (!fused)
        k_merge<<<256, 256, 0, stream>>>(Opart, Lpart, OT);
    k_proj<<<dim3(64, 4), 256, 0, stream>>>(OT, Opart, Lpart, fused,
                                            Wp16, bp, x, out);
}